// Round 5
// baseline (141.588 us; speedup 1.0000x reference)
//
#include <hip/hip_runtime.h>
#include <math.h>

#define BLOCK 256
#define NN 100

__device__ __forceinline__ float fast_rcp(float x) { return __builtin_amdgcn_rcpf(x); }

// one DPP max step: x = max(x, dpp_move(x)); masked-off lanes keep x (old=x)
template <int CTRL, int ROWMASK>
__device__ __forceinline__ float dpp_max(float x) {
    int xi = __float_as_int(x);
    int yi = __builtin_amdgcn_update_dpp(xi, xi, CTRL, ROWMASK, 0xf, true);
    return fmaxf(x, __int_as_float(yi));
}

// 64-lane max -> result lands in lane 63 (standard gfx9 row_shr/bcast idiom)
__device__ __forceinline__ float wave_max_to_lane63(float x) {
    x = dpp_max<0x111, 0xf>(x);   // row_shr:1
    x = dpp_max<0x112, 0xf>(x);   // row_shr:2
    x = dpp_max<0x114, 0xf>(x);   // row_shr:4
    x = dpp_max<0x118, 0xf>(x);   // row_shr:8 -> lane 15/31/47/63 = row maxes
    x = dpp_max<0x142, 0xa>(x);   // row_bcast15, rows 1&3
    x = dpp_max<0x143, 0xc>(x);   // row_bcast31, rows 2&3 -> lane 63 = wave max
    return x;
}

// ---------------------------------------------------------------------------
// Kernel 1: zero packed accumulators + precompute box areas.
// ---------------------------------------------------------------------------
__global__ void __launch_bounds__(BLOCK) bbp_init(
    unsigned long long* __restrict__ packed, float* __restrict__ areas,
    const float* __restrict__ bboxes, int n) {
    int i = blockIdx.x * BLOCK + threadIdx.x;
    if (i < n) {
        packed[i] = 0ull;
        float4 bb = *(const float4*)(bboxes + (size_t)i * 4);
        areas[i] = (bb.z - bb.x) * (bb.w - bb.y);
    }
}

// ---------------------------------------------------------------------------
// Kernel 2: per-anchor IoU rows; per-box column max via in-register DPP
// butterfly (no LDS tile, one barrier). Exact first-argmax semantics:
//  - row (per-anchor) argmax: strict > keeps first box
//  - column (per-box) argmax: equality ballot -> lowest lane; cross-wave and
//    cross-block combine via packed u64 (iou<<32 | ~anchor) max.
// ---------------------------------------------------------------------------
__global__ void __launch_bounds__(BLOCK, 4) bbp_match(
    const float* __restrict__ anchors,            // [A,4] cbox (cx,cy,w,h)
    const float* __restrict__ bboxes,             // [B,N,4] bbox
    const float* __restrict__ areas,              // [B,N]
    float* __restrict__ max_iou_anchor,           // [B,A]
    int* __restrict__ box_indice,                 // [B,A]
    int* __restrict__ winner,                     // [B,A] -> -1
    unsigned long long* __restrict__ packed,      // [B,N]
    int A, int N) {
    const int b = blockIdx.y;
    const int tid = threadIdx.x;
    const int a = blockIdx.x * BLOCK + tid;
    const int lane = tid & 63;
    const int wid = tid >> 6;
    const unsigned wavebase = (unsigned)(blockIdx.x * BLOCK + (tid & ~63));

    __shared__ unsigned long long spart[NN * 4];   // 3200 B

    const int aa = (a < A) ? a : (A - 1);
    const float4 ac = *(const float4*)(anchors + (size_t)aa * 4);
    const float ax1 = ac.x - ac.z * 0.5f;
    const float ay1 = ac.y - ac.w * 0.5f;
    const float ax2 = ac.x + ac.z * 0.5f;
    const float ay2 = ac.y + ac.w * 0.5f;
    const float area_a = (ax2 - ax1) * (ay2 - ay1);

    const float* bbase = bboxes + (size_t)b * NN * 4;  // wave-uniform
    const float* abase = areas + (size_t)b * NN;       // wave-uniform

    float best = -1.0f;
    int bi = 0;

    #pragma unroll 10
    for (int n = 0; n < NN; ++n) {
        const float4 bb = *(const float4*)(bbase + 4 * n);  // uniform -> s_load
        const float sa = abase[n];                          // uniform -> s_load
        float lx = fmaxf(ax1, bb.x), ly = fmaxf(ay1, bb.y);
        float rx = fminf(ax2, bb.z), ry = fminf(ay2, bb.w);
        float w = fmaxf(rx - lx, 0.0f), h = fmaxf(ry - ly, 0.0f);
        float inter = w * h;
        float iou = inter * fast_rcp(area_a + sa - inter);
        if (iou > best) { best = iou; bi = n; }   // strict > : first argmax

        // per-box wave max + first-lane argmax
        float wm = wave_max_to_lane63(iou);
        float wmax = __int_as_float(__builtin_amdgcn_readlane(__float_as_int(wm), 63));
        unsigned long long m = __ballot(iou == wmax);
        int first = __ffsll(m) - 1;               // lowest lane achieving max
        unsigned anch = wavebase + (unsigned)first;
        unsigned long long pk = ((unsigned long long)__float_as_uint(wmax) << 32)
                              | (unsigned long long)(0xFFFFFFFFu - anch);
        if (lane == 0) spart[n * 4 + wid] = pk;
    }
    __syncthreads();

    if (tid < NN) {
        unsigned long long m = spart[tid * 4];
        #pragma unroll
        for (int j = 1; j < 4; ++j) {
            unsigned long long o = spart[tid * 4 + j];
            if (o > m) m = o;
        }
        atomicMax(&packed[(size_t)b * N + tid], m);
    }

    if (a < A) {
        const size_t idx = (size_t)b * A + a;
        max_iou_anchor[idx] = best;
        box_indice[idx] = bi;
        winner[idx] = -1;
    }
}

// ---------------------------------------------------------------------------
// Kernel 3: segment_max(tgt_ids, anchor_indice) -> winner via atomicMax.
// ---------------------------------------------------------------------------
__global__ void __launch_bounds__(BLOCK) bbp_scatter(
    const unsigned long long* __restrict__ packed, int* __restrict__ winner,
    int A, int N, int B) {
    int i = blockIdx.x * BLOCK + threadIdx.x;
    if (i >= B * N) return;
    int b = i / N;
    int n = i - b * N;
    unsigned an = 0xFFFFFFFFu - (unsigned)(packed[i] & 0xFFFFFFFFull);
    if (an < (unsigned)A)
        atomicMax(&winner[(size_t)b * A + an], n);
}

// ---------------------------------------------------------------------------
// Kernel 4: apply override, score, one-hot conf, delta encoding.
// ---------------------------------------------------------------------------
__global__ void __launch_bounds__(BLOCK) bbp_finalize(
    const float* __restrict__ anchors, const float* __restrict__ bboxes,
    const int* __restrict__ labels, const float* __restrict__ mean4,
    const float* __restrict__ std4, const float* __restrict__ thr_p,
    const float* __restrict__ max_iou_anchor, const int* __restrict__ box_indice,
    const int* __restrict__ winner, const unsigned long long* __restrict__ packed,
    float* __restrict__ out_conf, float* __restrict__ out_deltas,
    int A, int N, int C) {
    const int b = blockIdx.y;
    const int a = blockIdx.x * BLOCK + threadIdx.x;
    if (a >= A) return;
    const float thr = thr_p[0];
    const size_t idx = (size_t)b * A + a;

    int w = winner[idx];
    bool valid = (w >= 0);
    int bi = valid ? w : box_indice[idx];
    float miou = valid ? __uint_as_float((unsigned)(packed[(size_t)b * N + w] >> 32))
                       : max_iou_anchor[idx];
    float mb = __uint_as_float((unsigned)(packed[(size_t)b * N + bi] >> 32));
    float denom = fmaxf(mb, thr);
    if (miou < thr * 0.5f) miou = 0.0f;
    float score = miou * fast_rcp(denom);
    int lab = labels[(size_t)b * N + bi];
    if (lab <= 0) { score = 0.0f; lab = 0; }

    for (int c = 0; c < C; ++c)
        out_conf[idx * C + c] = (lab == c + 1) ? score : 0.0f;

    float4 bb = *(const float4*)(bboxes + ((size_t)b * N + bi) * 4);
    float4 ac = *(const float4*)(anchors + (size_t)a * 4);
    float cx = (bb.x + bb.z) * 0.5f;
    float cy = (bb.y + bb.w) * 0.5f;
    float bw = bb.z - bb.x;
    float bh = bb.w - bb.y;
    const float rz = fast_rcp(ac.z), rw = fast_rcp(ac.w);
    float4 d;
    d.x = ((cx - ac.x) * rz - mean4[0]) * fast_rcp(std4[0]);
    d.y = ((cy - ac.y) * rw - mean4[1]) * fast_rcp(std4[1]);
    d.z = (__logf(bw * rz) - mean4[2]) * fast_rcp(std4[2]);
    d.w = (__logf(bh * rw) - mean4[3]) * fast_rcp(std4[3]);
    *(float4*)(out_deltas + idx * 4) = d;
}

// ---------------------------------------------------------------------------
extern "C" void kernel_launch(void* const* d_in, const int* in_sizes, int n_in,
                              void* d_out, int out_size, void* d_ws, size_t ws_size,
                              hipStream_t stream) {
    const float* anchors = (const float*)d_in[0];
    const int* labels = (const int*)d_in[1];
    const float* bboxes = (const float*)d_in[2];
    const float* mean4 = (const float*)d_in[3];
    const float* std4 = (const float*)d_in[4];
    const float* thr_p = (const float*)d_in[5];

    const int A = in_sizes[0] / 4;        // 65536
    const int BN = in_sizes[1];           // 800
    const int N = NN;                     // 100
    const int B = BN / N;                 // 8
    const int C = out_size / (B * A) - 4; // 1

    char* ws = (char*)d_ws;
    unsigned long long* packed = (unsigned long long*)ws;                      // [B*N]
    size_t off = ((size_t)B * N * sizeof(unsigned long long) + 255) & ~(size_t)255;
    float* areas = (float*)(ws + off); off += (size_t)B * N * sizeof(float);
    off = (off + 255) & ~(size_t)255;
    float* max_iou_anchor = (float*)(ws + off); off += (size_t)B * A * sizeof(float);
    off = (off + 255) & ~(size_t)255;
    int* box_indice = (int*)(ws + off); off += (size_t)B * A * sizeof(int);
    off = (off + 255) & ~(size_t)255;
    int* winner = (int*)(ws + off);

    float* out_conf = (float*)d_out;
    float* out_deltas = out_conf + (size_t)B * A * C;

    bbp_init<<<dim3((B * N + BLOCK - 1) / BLOCK), dim3(BLOCK), 0, stream>>>(
        packed, areas, bboxes, B * N);

    dim3 grid((A + BLOCK - 1) / BLOCK, B);
    bbp_match<<<grid, dim3(BLOCK), 0, stream>>>(anchors, bboxes, areas, max_iou_anchor,
                                                box_indice, winner, packed, A, N);

    bbp_scatter<<<dim3((B * N + BLOCK - 1) / BLOCK), dim3(BLOCK), 0, stream>>>(
        packed, winner, A, N, B);

    bbp_finalize<<<grid, dim3(BLOCK), 0, stream>>>(anchors, bboxes, labels, mean4, std4,
                                                   thr_p, max_iou_anchor, box_indice,
                                                   winner, packed, out_conf, out_deltas,
                                                   A, N, C);
}